// Round 6
// baseline (513.302 us; speedup 1.0000x reference)
//
#include <hip/hip_runtime.h>
#include <hip/hip_bf16.h>

// B=8, T=2048, E=1024 single-head attention, bf16 MFMA pipeline, round 8:
// round-7 fused-softmax pipeline with (a) phase emission reverted to the
// round-5 form {stage; ds_reads; waitcnt+s_barrier fused; MFMA} (r7's
// two-barrier m201 order measured +4% slower), and (b) split counted
// waits: p2 vmcnt(10) confirms Ak1(t) (age 5 phases), p4 vmcnt(8)
// confirms Bk0/Ak0/Bk1(t+1) (ages 6/5/4) — min prefetch slack 3->4
// phases, no extra LDS. FIFO invariant: 8 loads outstanding after each
// p4 wait = {Ak1(t+1), Bk0/Ak0/Bk1(t+2)}.
typedef __attribute__((ext_vector_type(8))) short short8;
typedef __attribute__((ext_vector_type(8))) unsigned short ushortx8;
typedef __attribute__((ext_vector_type(4))) unsigned short ushortx4;
typedef __attribute__((ext_vector_type(4))) float floatx4;

#define NB 8
#define NT 2048
#define NE 1024

__device__ __forceinline__ unsigned short f2bf(float f){
  unsigned int u = __builtin_bit_cast(unsigned int, f);
  u += 0x7FFFu + ((u >> 16) & 1u);          // RNE; inputs finite
  return (unsigned short)(u >> 16);
}
__device__ __forceinline__ float bf2f(unsigned short h){
  unsigned int u = ((unsigned int)h) << 16;
  return __builtin_bit_cast(float, u);
}

__device__ __forceinline__ void async16(void* lds, const void* g){
  __builtin_amdgcn_global_load_lds(
      (const __attribute__((address_space(1))) unsigned int*)g,
      (__attribute__((address_space(3))) unsigned int*)lds, 16, 0, 0);
}

#define MFMA16(d, va, vb) \
  d = __builtin_amdgcn_mfma_f32_16x16x32_bf16(va, vb, d, 0, 0, 0)

// ---------------- fp32 -> bf16 convert, 3 sources ----------------
__global__ __launch_bounds__(256) void cvt3(const float* __restrict__ a0,
                                            const float* __restrict__ a1,
                                            const float* __restrict__ a2,
                                            unsigned short* __restrict__ out,
                                            int n4_per){
  const float* src = blockIdx.y == 0 ? a0 : (blockIdx.y == 1 ? a1 : a2);
  unsigned short* dst = out + (size_t)blockIdx.y * (size_t)n4_per * 4;
  int i = blockIdx.x * 256 + threadIdx.x;
  if (i < n4_per){
    floatx4 f = ((const floatx4*)src)[i];
    ushortx4 o;
    o.x = f2bf(f.x); o.y = f2bf(f.y); o.z = f2bf(f.z); o.w = f2bf(f.w);
    *(ushortx4*)(dst + (size_t)i * 4) = o;
  }
}

// ---------------- mask [2048][2048] int32 -> bitmask (512 KB) ----------------
__global__ __launch_bounds__(256) void pack_mask(const int* __restrict__ m,
                                                 unsigned long long* __restrict__ bits){
  int t = blockIdx.x * 256 + threadIdx.x;          // 65536 words
  const int4* p = (const int4*)(m + (size_t)t * 64);
  unsigned long long w = 0;
  #pragma unroll
  for (int jj = 0; jj < 16; jj++){
    int4 v = p[jj];
    w |= (unsigned long long)(v.x != 0) << (jj * 4 + 0);
    w |= (unsigned long long)(v.y != 0) << (jj * 4 + 1);
    w |= (unsigned long long)(v.z != 0) << (jj * 4 + 2);
    w |= (unsigned long long)(v.w != 0) << (jj * 4 + 3);
  }
  bits[t] = w;
}

// ---------------- NT GEMM: C[m,n] = sum_k A[m,k]*B[n,k], all bf16 in ----------------
// Tile 256x256, BK=64, 512 threads = 8 waves (wm=wave>>2 in M, wn=wave&3 in N);
// per-wave 128x64 output = acc[8][4] of 16x16x32 MFMAs.
// LDS 128 KB: [dbuf][A|B][khalf] 16 KB units, rows of 64 B (32 bf16).
// Chunk swizzle: logical chunk c of row r stored at physical slot c^((r>>1)&3)
// (verified 0 bank conflicts, r5). Staging: linear-LDS global_load_lds with
// the inverse swizzle applied to the per-lane GLOBAL address.
// Phase body (r5-verified order): {stage 1 unit; ds_read frags;
// [vmcnt]+lgkm0+s_barrier fused; sched_barrier; setprio 16xMFMA}.
// Wait schedule (split counted): p2 vmcnt(10) -> confirms Ak1(t) for p3's
// reads; p4 vmcnt(8) -> confirms Bk0/Ak0/Bk1(t+1) for t+1.p1's reads.
// Tail: t+2==NK: p2 vmcnt(8), p4 vmcnt(0); t+1==NK: lgkm0 only.
// EPI 0: store bf16. EPI 1: e = mask ? exp(v/32) : 0, store bf16, atomic
// per-row sum. EPI 2: fp32 out scaled by 1/rowsum[row].
template<int EPI>
__global__ __launch_bounds__(512, 2) void gemm_nt(
    const unsigned short* __restrict__ A, long strideA,
    const unsigned short* __restrict__ B, long strideB,
    void* __restrict__ Out, long strideOutBytes,
    const unsigned long long* __restrict__ mbits,
    float* __restrict__ rowsums,
    int K, int gx, int gy)
{
  __shared__ __attribute__((aligned(16))) char Lds[131072];
  const int tid = threadIdx.x;
  const int lane = tid & 63, wave = tid >> 6;

  // XCD-aware decode: L%8 = XCD; all gx n-tiles of one A-strip on one XCD.
  int L = blockIdx.x;
  int xcd = L & 7, tt = L >> 3;
  int x = tt % gx;
  int strip = xcd + ((tt / gx) << 3);
  int y = strip % gy, z = strip / gy;
  const int m0 = y << 8, n0 = x << 8;
  const int Nn = gx << 8;

  const unsigned short* Az = A + (size_t)z * strideA;
  const unsigned short* Bz = B + (size_t)z * strideB;

  // Staging: unit = 16 KB = 1024 slots of 16B; thread covers slots tid and
  // tid+512. slot s: r = s>>2 (row; +128 for the second), cs = s&3,
  // logical chunk c = cs ^ ((r>>1)&3)  [invariant under r+128].
  const long rowb  = (long)K * 2;       // bytes per A/B row
  const long rs128 = rowb << 7;         // 128 rows
  const int r0 = tid >> 2;
  const int c0 = (tid & 3) ^ ((r0 >> 1) & 3);
  const char* pA0 = (const char*)Az + (size_t)(m0 + r0) * rowb + (c0 << 4);      // k-half 0
  const char* pA1 = pA0 + 64;                                                    // k-half 1
  const char* pB0 = (const char*)Bz + (size_t)(n0 + r0) * rowb + (c0 << 4);
  const char* pB1 = pB0 + 64;
  const int stg = tid << 4;

  auto stageU = [&](const char*& g, int ldsoff){
    async16(Lds + ldsoff + stg,        g);
    async16(Lds + ldsoff + stg + 8192, g + rs128);
    g += 128;                           // advance one K-tile (BK=64 bf16)
  };

  // Fragment reads: row = (warp base) + mi*16 + lm, logical chunk qd at
  // physical slot qd ^ ((row>>1)&3) = qd ^ ((lm>>1)&3).
  const int lm = lane & 15, qd = lane >> 4;
  const int wm = wave >> 2, wn = wave & 3;          // 2 (M) x 4 (N)
  const int fsw  = (qd ^ ((lm >> 1) & 3)) << 4;
  const int aoff = ((wm << 7) + lm) * 64 + fsw;               // + mi*1024 + kh*16384 + dbuf
  const int boff = 32768 + ((wn << 6) + lm) * 64 + fsw;       // + ni*1024 + kh*16384 + dbuf

  floatx4 acc[8][4];
  floatx4 zero4 = {0.f, 0.f, 0.f, 0.f};
  #pragma unroll
  for (int a = 0; a < 8; a++)
    #pragma unroll
    for (int b = 0; b < 4; b++) acc[a][b] = zero4;

  const int NK = K >> 6;

  // Prologue: tile0 all 4 units, tile1 {B-k0, A-k0, B-k1} (A-k1(1) comes at
  // t=0.p1). vmcnt(6) confirms tile0's 8 loads, leaves tile1's 6 in flight.
  stageU(pB0, 32768);                     // B-k0(0) dbuf0
  stageU(pA0, 0);                         // A-k0(0)
  stageU(pB1, 32768 + 16384);             // B-k1(0)
  stageU(pA1, 16384);                     // A-k1(0)
  stageU(pB0, 65536 + 32768);             // B-k0(1) dbuf1
  stageU(pA0, 65536);                     // A-k0(1)
  stageU(pB1, 65536 + 32768 + 16384);     // B-k1(1)
  asm volatile("s_waitcnt vmcnt(6)\n\ts_barrier" ::: "memory");

  short8 a[4], b[4];
  for (int t = 0; t < NK; ++t){
    const int rb = (t & 1) << 16;         // read dbuf (and t+2 stage dbuf)
    const int sb = rb ^ 65536;            // t+1 stage dbuf

    // ---- phase 1: kh=0, mi 0-3 (+ all B kh=0) ----
    if (t + 1 < NK) stageU(pA1, sb + 16384);
    #pragma unroll
    for (int j = 0; j < 4; j++) a[j] = *(const short8*)(Lds + rb + aoff + j * 1024);
    #pragma unroll
    for (int n = 0; n < 4; n++) b[n] = *(const short8*)(Lds + rb + boff + n * 1024);
    asm volatile("s_waitcnt lgkmcnt(0)\n\ts_barrier" ::: "memory");
    __builtin_amdgcn_sched_barrier(0);
    __builtin_amdgcn_s_setprio(1);
    #pragma unroll
    for (int j = 0; j < 4; j++)
      #pragma unroll
      for (int n = 0; n < 4; n++) MFMA16(acc[j][n], a[j], b[n]);
    __builtin_amdgcn_s_setprio(0);

    // ---- phase 2: kh=0, mi 4-7; vmcnt(10) confirms Ak1(t) for p3 ----
    if (t + 2 < NK) stageU(pB0, rb + 32768);
    #pragma unroll
    for (int j = 0; j < 4; j++) a[j] = *(const short8*)(Lds + rb + aoff + (4 + j) * 1024);
    if (t + 2 < NK)
      asm volatile("s_waitcnt vmcnt(10) lgkmcnt(0)\n\ts_barrier" ::: "memory");
    else if (t + 1 < NK)
      asm volatile("s_waitcnt vmcnt(8) lgkmcnt(0)\n\ts_barrier" ::: "memory");
    else
      asm volatile("s_waitcnt lgkmcnt(0)\n\ts_barrier" ::: "memory");
    __builtin_amdgcn_sched_barrier(0);
    __builtin_amdgcn_s_setprio(1);
    #pragma unroll
    for (int j = 0; j < 4; j++)
      #pragma unroll
      for (int n = 0; n < 4; n++) MFMA16(acc[4 + j][n], a[j], b[n]);
    __builtin_amdgcn_s_setprio(0);

    // ---- phase 3: kh=1, mi 0-3 (+ all B kh=1) ----
    if (t + 2 < NK) stageU(pA0, rb);
    #pragma unroll
    for (int j = 0; j < 4; j++) a[j] = *(const short8*)(Lds + rb + 16384 + aoff + j * 1024);
    #pragma unroll
    for (int n = 0; n < 4; n++) b[n] = *(const short8*)(Lds + rb + 16384 + boff + n * 1024);
    asm volatile("s_waitcnt lgkmcnt(0)\n\ts_barrier" ::: "memory");
    __builtin_amdgcn_sched_barrier(0);
    __builtin_amdgcn_s_setprio(1);
    #pragma unroll
    for (int j = 0; j < 4; j++)
      #pragma unroll
      for (int n = 0; n < 4; n++) MFMA16(acc[j][n], a[j], b[n]);
    __builtin_amdgcn_s_setprio(0);

    // ---- phase 4: kh=1, mi 4-7; vmcnt(8) confirms Bk0/Ak0/Bk1(t+1) ----
    #pragma unroll
    for (int j = 0; j < 4; j++) a[j] = *(const short8*)(Lds + rb + 16384 + aoff + (4 + j) * 1024);
    if (t + 2 < NK){
      stageU(pB1, rb + 32768 + 16384);
      asm volatile("s_waitcnt vmcnt(8) lgkmcnt(0)\n\ts_barrier" ::: "memory");
    } else {
      asm volatile("s_waitcnt vmcnt(0) lgkmcnt(0)\n\ts_barrier" ::: "memory");
    }
    __builtin_amdgcn_sched_barrier(0);
    __builtin_amdgcn_s_setprio(1);
    #pragma unroll
    for (int j = 0; j < 4; j++)
      #pragma unroll
      for (int n = 0; n < 4; n++) MFMA16(acc[4 + j][n], a[j], b[n]);
    __builtin_amdgcn_s_setprio(0);
  }

  // Epilogue. C/D layout: col = lane&15, row = (lane>>4)*4 + i  (m89/m91).
  char* OutZ = (char*)Out + (size_t)z * strideOutBytes;
  const int colbase = n0 + (wn << 6);
  if constexpr (EPI == 1){
    const int wcol = colbase >> 6;
    #pragma unroll
    for (int mi = 0; mi < 8; mi++){
      #pragma unroll
      for (int i = 0; i < 4; i++){
        int row = m0 + (wm << 7) + mi * 16 + qd * 4 + i;
        unsigned long long w = mbits[(size_t)row * (NT / 64) + wcol];
        unsigned short* po = (unsigned short*)OutZ + (size_t)row * Nn + colbase;
        float rsum = 0.f;
        #pragma unroll
        for (int ni = 0; ni < 4; ni++){
          float vv = acc[mi][ni][i];
          float e = ((w >> (ni * 16 + lm)) & 1ull) ? __expf(vv * 0.03125f) : 0.f;
          rsum += e;
          po[ni * 16 + lm] = f2bf(e);
        }
        // reduce across the 16 lanes (lm) of this qd group -> row total (64 cols)
        rsum += __shfl_xor(rsum, 1, 64);
        rsum += __shfl_xor(rsum, 2, 64);
        rsum += __shfl_xor(rsum, 4, 64);
        rsum += __shfl_xor(rsum, 8, 64);
        if (lm == 0) atomicAdd(rowsums + ((size_t)z << 11) + row, rsum);
      }
    }
  } else if constexpr (EPI == 2){
    #pragma unroll
    for (int mi = 0; mi < 8; mi++){
      #pragma unroll
      for (int i = 0; i < 4; i++){
        int row = m0 + (wm << 7) + mi * 16 + qd * 4 + i;
        float inv = 1.0f / rowsums[((size_t)z << 11) + row];
        #pragma unroll
        for (int ni = 0; ni < 4; ni++){
          int col = colbase + ni * 16 + lm;
          ((float*)OutZ)[(size_t)row * Nn + col] = acc[mi][ni][i] * inv;
        }
      }
    }
  } else {
    #pragma unroll
    for (int mi = 0; mi < 8; mi++){
      #pragma unroll
      for (int i = 0; i < 4; i++){
        int row = m0 + (wm << 7) + mi * 16 + qd * 4 + i;
        #pragma unroll
        for (int ni = 0; ni < 4; ni++){
          int col = colbase + ni * 16 + lm;
          ((unsigned short*)OutZ)[(size_t)row * Nn + col] = f2bf(acc[mi][ni][i]);
        }
      }
    }
  }
}

// -------- bf16 transpose (per batch): [rows][cols] -> [cols][rows] --------
// Also zeroes the rowsums buffer (dead-Wb overlay) before the QK^T GEMM.
__global__ __launch_bounds__(256) void transpose_bf16(const unsigned short* __restrict__ in,
                                                      unsigned short* __restrict__ out,
                                                      float* __restrict__ rowsums,
                                                      int rows, int cols){
  __shared__ __attribute__((aligned(16))) unsigned short tile[64][72];
  const unsigned short* ib = in + (size_t)blockIdx.z * rows * cols;
  unsigned short* ob = out + (size_t)blockIdx.z * rows * cols;
  int r0 = blockIdx.x * 64;
  int c0 = blockIdx.y * 64;
  int tid = threadIdx.x;
  if (blockIdx.x == 0 && blockIdx.y == 0){
    float* rz = rowsums + ((size_t)blockIdx.z << 11);
    #pragma unroll
    for (int i = 0; i < 8; i++) rz[tid + i * 256] = 0.f;
  }
  #pragma unroll
  for (int i = 0; i < 2; i++){
    int id = tid + i * 256;
    int r = id >> 3, c = (id & 7) * 8;
    ushortx8 v = *(const ushortx8*)(ib + (size_t)(r0 + r) * cols + c0 + c);
    *(ushortx8*)&tile[r][c] = v;
  }
  __syncthreads();
  #pragma unroll
  for (int i = 0; i < 2; i++){
    int id = tid + i * 256;
    int r = id >> 3, c = (id & 7) * 8;
    ushortx8 v;
    #pragma unroll
    for (int j = 0; j < 8; j++) v[j] = tile[c + j][r];
    *(ushortx8*)(ob + (size_t)(c0 + r) * rows + r0 + c) = v;
  }
}

extern "C" void kernel_launch(void* const* d_in, const int* in_sizes, int n_in,
                              void* d_out, int out_size, void* d_ws, size_t ws_size,
                              hipStream_t stream){
  const float* q  = (const float*)d_in[0];
  const float* k  = (const float*)d_in[1];
  const float* v  = (const float*)d_in[2];
  const int* mask = (const int*)d_in[3];
  const float* Wq = (const float*)d_in[4];
  const float* Wk = (const float*)d_in[5];
  const float* Wv = (const float*)d_in[6];

  const size_t BTE = (size_t)NB * NT * NE;     // 16,777,216
  unsigned short* ws   = (unsigned short*)d_ws;
  unsigned short* QKVp = ws;                                    // [3][B*T][E]
  unsigned short* VpT  = ws + 3 * BTE;                          // [B][E][T]
  unsigned short* Sb   = ws + 3 * BTE + BTE;                    // [B][T][T]
  unsigned short* Qin  = ws + 3 * BTE;                          // aliases VpT+Sb (3*BTE)
  unsigned short* Wb   = ws + 3 * BTE + BTE + (size_t)NB * NT * NT;  // [3][E][E]
  unsigned long long* mbits = (unsigned long long*)(Wb + (size_t)3 * NE * NE);
  // rowsums [NB][NT] f32 (64 KB) OVERLAYS Wb (dead after projections) --
  // keeps workspace high-water mark identical to the verified r5 layout.
  float* rowsums = (float*)Wb;

  unsigned short* Qp = QKVp;
  unsigned short* Kp = QKVp + BTE;
  unsigned short* Vp = QKVp + 2 * BTE;

  // 1) fp32 -> bf16: inputs q,k,v (Qin aliases the region later used by VpT|Sb)
  cvt3<<<dim3(16384, 3), 256, 0, stream>>>(q, k, v, Qin, (int)(BTE / 4));
  // 2) weights -> bf16
  cvt3<<<dim3(1024, 3), 256, 0, stream>>>(Wq, Wk, Wv, Wb, NE * NE / 4);
  // 3) mask -> bitmask
  pack_mask<<<256, 256, 0, stream>>>(mask, mbits);

  // 4) projections: [3 x] (16384 x 1024 x 1024); gx=4, gy=64, gz=3
  gemm_nt<0><<<768, 512, 0, stream>>>(
      Qin, (long)BTE, Wb, (long)NE * NE,
      QKVp, (long)BTE * 2, nullptr, nullptr, NE, 4, 64);

  // 5) V -> V^T per batch (overwrites Qin's q-part); also zeroes rowsums
  //    (Wb is dead from here on).
  transpose_bf16<<<dim3(32, 16, 8), 256, 0, stream>>>(Vp, VpT, rowsums, NT, NE);

  // 6) S' = mask ? exp(QK^T/32) : 0, + per-row sums; gx=8, gy=8, gz=8
  gemm_nt<1><<<512, 512, 0, stream>>>(
      Qp, (long)NT * NE, Kp, (long)NT * NE,
      Sb, (long)NT * NT * 2, mbits, rowsums, NE, 8, 8);

  // 7) O = (S' V) / rowsum; gx=4, gy=8, gz=8, fp32 out
  gemm_nt<2><<<256, 512, 0, stream>>>(
      Sb, (long)NT * NT, VpT, (long)NE * NT,
      d_out, (long)NT * NE * 4, nullptr, rowsums, NT, 4, 8);
}

// Round 7
// 498.112 us; speedup vs baseline: 1.0305x; 1.0305x over previous
//
#include <hip/hip_runtime.h>
#include <hip/hip_bf16.h>

// B=8, T=2048, E=1024 single-head attention, bf16 MFMA pipeline, round 9:
// GEMM K-loop identical to round 8 (schedule lever exhausted: r5/r7/r8 all
// 109-114 µs). Pipeline cuts instead:
//  - V^T fused into V-proj epilogue (LDS transpose, coalesced 16B stores);
//    transpose_bf16 dispatch deleted; V^T lives in Vp's old slot (no
//    workspace growth, no overlap with Qin-q which proj still reads).
//  - weight-cvt + mask-pack merged into one prep kernel.
//  - rowsums zeroed via hipMemsetAsync after proj (Wb-overlay unchanged).
typedef __attribute__((ext_vector_type(8))) short short8;
typedef __attribute__((ext_vector_type(8))) unsigned short ushortx8;
typedef __attribute__((ext_vector_type(4))) unsigned short ushortx4;
typedef __attribute__((ext_vector_type(4))) float floatx4;
typedef __attribute__((ext_vector_type(2))) unsigned int uint2v;

#define NB 8
#define NT 2048
#define NE 1024

__device__ __forceinline__ unsigned short f2bf(float f){
  unsigned int u = __builtin_bit_cast(unsigned int, f);
  u += 0x7FFFu + ((u >> 16) & 1u);          // RNE; inputs finite
  return (unsigned short)(u >> 16);
}

__device__ __forceinline__ void async16(void* lds, const void* g){
  __builtin_amdgcn_global_load_lds(
      (const __attribute__((address_space(1))) unsigned int*)g,
      (__attribute__((address_space(3))) unsigned int*)lds, 16, 0, 0);
}

#define MFMA16(d, va, vb) \
  d = __builtin_amdgcn_mfma_f32_16x16x32_bf16(va, vb, d, 0, 0, 0)

// ---------------- fp32 -> bf16 convert, 3 sources (q,k,v) ----------------
__global__ __launch_bounds__(256) void cvt3(const float* __restrict__ a0,
                                            const float* __restrict__ a1,
                                            const float* __restrict__ a2,
                                            unsigned short* __restrict__ out,
                                            int n4_per){
  const float* src = blockIdx.y == 0 ? a0 : (blockIdx.y == 1 ? a1 : a2);
  unsigned short* dst = out + (size_t)blockIdx.y * (size_t)n4_per * 4;
  int i = blockIdx.x * 256 + threadIdx.x;
  if (i < n4_per){
    floatx4 f = ((const floatx4*)src)[i];
    ushortx4 o;
    o.x = f2bf(f.x); o.y = f2bf(f.y); o.z = f2bf(f.z); o.w = f2bf(f.w);
    *(ushortx4*)(dst + (size_t)i * 4) = o;
  }
}

// ------ prep: weights fp32->bf16 (blocks 0..3071) + mask bitpack (3072..3327) ------
__global__ __launch_bounds__(256) void prep(const float* __restrict__ w0,
                                            const float* __restrict__ w1,
                                            const float* __restrict__ w2,
                                            unsigned short* __restrict__ wout,
                                            const int* __restrict__ m,
                                            unsigned long long* __restrict__ bits){
  int bx = blockIdx.x;
  if (bx < 3072){
    int y = bx >> 10;
    int i = ((bx & 1023) << 8) + threadIdx.x;         // 0..262143 per weight
    const float* src = y == 0 ? w0 : (y == 1 ? w1 : w2);
    floatx4 f = ((const floatx4*)src)[i];
    ushortx4 o;
    o.x = f2bf(f.x); o.y = f2bf(f.y); o.z = f2bf(f.z); o.w = f2bf(f.w);
    *(ushortx4*)(wout + (size_t)y * (NE * NE) + (size_t)i * 4) = o;
  } else {
    int t = ((bx - 3072) << 8) + threadIdx.x;         // 0..65535 words
    const int4* p = (const int4*)(m + (size_t)t * 64);
    unsigned long long w = 0;
    #pragma unroll
    for (int jj = 0; jj < 16; jj++){
      int4 v = p[jj];
      w |= (unsigned long long)(v.x != 0) << (jj * 4 + 0);
      w |= (unsigned long long)(v.y != 0) << (jj * 4 + 1);
      w |= (unsigned long long)(v.z != 0) << (jj * 4 + 2);
      w |= (unsigned long long)(v.w != 0) << (jj * 4 + 3);
    }
    bits[t] = w;
  }
}

// ---------------- NT GEMM: C[m,n] = sum_k A[m,k]*B[n,k], all bf16 in ----------------
// Tile 256x256, BK=64, 512 threads = 8 waves (wm=wave>>2 in M, wn=wave&3 in N);
// per-wave 128x64 output = acc[8][4] of 16x16x32 MFMAs.
// LDS 128 KB pipeline region: [dbuf][A|B][khalf] 16 KB units, 64-B rows.
// Chunk swizzle: logical chunk c of row r at physical slot c^((r>>1)&3)
// (verified 0 bank conflicts). Staging: linear-LDS global_load_lds with the
// inverse swizzle on the per-lane GLOBAL address.
// Phase body (r5/r8-verified): {stage 1 unit; ds_read frags;
// [vmcnt]+lgkm0+s_barrier fused; sched_barrier; setprio 16xMFMA}.
// Waits: p2 vmcnt(10) confirms Ak1(t); p4 vmcnt(8) confirms Bk0/Ak0/Bk1(t+1).
// EPI 0: store bf16; if z==2 && trOut: LDS-transpose and store to trOut
//        ([emb][token] per batch) instead — fused V^T.
// EPI 1: e = mask ? exp(v/32) : 0, store bf16, atomic per-row sum.
// EPI 2: fp32 out scaled by 1/rowsum[row].
template<int EPI>
__global__ __launch_bounds__(512, 2) void gemm_nt(
    const unsigned short* __restrict__ A, long strideA,
    const unsigned short* __restrict__ B, long strideB,
    void* __restrict__ Out, long strideOutBytes,
    const unsigned long long* __restrict__ mbits,
    float* __restrict__ rowsums,
    unsigned short* __restrict__ trOut,
    int K, int gx, int gy)
{
  __shared__ __attribute__((aligned(16))) char Lds[135168];  // 128K pipe + pad for epi-transpose
  const int tid = threadIdx.x;
  const int lane = tid & 63, wave = tid >> 6;

  // XCD-aware decode: L%8 = XCD; all gx n-tiles of one A-strip on one XCD.
  int L = blockIdx.x;
  int xcd = L & 7, tt = L >> 3;
  int x = tt % gx;
  int strip = xcd + ((tt / gx) << 3);
  int y = strip % gy, z = strip / gy;
  const int m0 = y << 8, n0 = x << 8;
  const int Nn = gx << 8;

  const unsigned short* Az = A + (size_t)z * strideA;
  const unsigned short* Bz = B + (size_t)z * strideB;

  // Staging: unit = 16 KB = 1024 slots of 16B; thread covers slots tid and
  // tid+512. slot s: r = s>>2 (row; +128 for the second), cs = s&3,
  // logical chunk c = cs ^ ((r>>1)&3)  [invariant under r+128].
  const long rowb  = (long)K * 2;       // bytes per A/B row
  const long rs128 = rowb << 7;         // 128 rows
  const int r0 = tid >> 2;
  const int c0 = (tid & 3) ^ ((r0 >> 1) & 3);
  const char* pA0 = (const char*)Az + (size_t)(m0 + r0) * rowb + (c0 << 4);      // k-half 0
  const char* pA1 = pA0 + 64;                                                    // k-half 1
  const char* pB0 = (const char*)Bz + (size_t)(n0 + r0) * rowb + (c0 << 4);
  const char* pB1 = pB0 + 64;
  const int stg = tid << 4;

  auto stageU = [&](const char*& g, int ldsoff){
    async16(Lds + ldsoff + stg,        g);
    async16(Lds + ldsoff + stg + 8192, g + rs128);
    g += 128;                           // advance one K-tile (BK=64 bf16)
  };

  // Fragment reads: row = (warp base) + mi*16 + lm, logical chunk qd at
  // physical slot qd ^ ((row>>1)&3) = qd ^ ((lm>>1)&3).
  const int lm = lane & 15, qd = lane >> 4;
  const int wm = wave >> 2, wn = wave & 3;          // 2 (M) x 4 (N)
  const int fsw  = (qd ^ ((lm >> 1) & 3)) << 4;
  const int aoff = ((wm << 7) + lm) * 64 + fsw;               // + mi*1024 + kh*16384 + dbuf
  const int boff = 32768 + ((wn << 6) + lm) * 64 + fsw;       // + ni*1024 + kh*16384 + dbuf

  floatx4 acc[8][4];
  floatx4 zero4 = {0.f, 0.f, 0.f, 0.f};
  #pragma unroll
  for (int a = 0; a < 8; a++)
    #pragma unroll
    for (int b = 0; b < 4; b++) acc[a][b] = zero4;

  const int NK = K >> 6;

  // Prologue: tile0 all 4 units, tile1 {B-k0, A-k0, B-k1} (A-k1(1) comes at
  // t=0.p1). vmcnt(6) confirms tile0's 8 loads, leaves tile1's 6 in flight.
  stageU(pB0, 32768);                     // B-k0(0) dbuf0
  stageU(pA0, 0);                         // A-k0(0)
  stageU(pB1, 32768 + 16384);             // B-k1(0)
  stageU(pA1, 16384);                     // A-k1(0)
  stageU(pB0, 65536 + 32768);             // B-k0(1) dbuf1
  stageU(pA0, 65536);                     // A-k0(1)
  stageU(pB1, 65536 + 32768 + 16384);     // B-k1(1)
  asm volatile("s_waitcnt vmcnt(6)\n\ts_barrier" ::: "memory");

  short8 a[4], b[4];
  for (int t = 0; t < NK; ++t){
    const int rb = (t & 1) << 16;         // read dbuf (and t+2 stage dbuf)
    const int sb = rb ^ 65536;            // t+1 stage dbuf

    // ---- phase 1: kh=0, mi 0-3 (+ all B kh=0) ----
    if (t + 1 < NK) stageU(pA1, sb + 16384);
    #pragma unroll
    for (int j = 0; j < 4; j++) a[j] = *(const short8*)(Lds + rb + aoff + j * 1024);
    #pragma unroll
    for (int n = 0; n < 4; n++) b[n] = *(const short8*)(Lds + rb + boff + n * 1024);
    asm volatile("s_waitcnt lgkmcnt(0)\n\ts_barrier" ::: "memory");
    __builtin_amdgcn_sched_barrier(0);
    __builtin_amdgcn_s_setprio(1);
    #pragma unroll
    for (int j = 0; j < 4; j++)
      #pragma unroll
      for (int n = 0; n < 4; n++) MFMA16(acc[j][n], a[j], b[n]);
    __builtin_amdgcn_s_setprio(0);

    // ---- phase 2: kh=0, mi 4-7; vmcnt(10) confirms Ak1(t) for p3 ----
    if (t + 2 < NK) stageU(pB0, rb + 32768);
    #pragma unroll
    for (int j = 0; j < 4; j++) a[j] = *(const short8*)(Lds + rb + aoff + (4 + j) * 1024);
    if (t + 2 < NK)
      asm volatile("s_waitcnt vmcnt(10) lgkmcnt(0)\n\ts_barrier" ::: "memory");
    else if (t + 1 < NK)
      asm volatile("s_waitcnt vmcnt(8) lgkmcnt(0)\n\ts_barrier" ::: "memory");
    else
      asm volatile("s_waitcnt lgkmcnt(0)\n\ts_barrier" ::: "memory");
    __builtin_amdgcn_sched_barrier(0);
    __builtin_amdgcn_s_setprio(1);
    #pragma unroll
    for (int j = 0; j < 4; j++)
      #pragma unroll
      for (int n = 0; n < 4; n++) MFMA16(acc[4 + j][n], a[j], b[n]);
    __builtin_amdgcn_s_setprio(0);

    // ---- phase 3: kh=1, mi 0-3 (+ all B kh=1) ----
    if (t + 2 < NK) stageU(pA0, rb);
    #pragma unroll
    for (int j = 0; j < 4; j++) a[j] = *(const short8*)(Lds + rb + 16384 + aoff + j * 1024);
    #pragma unroll
    for (int n = 0; n < 4; n++) b[n] = *(const short8*)(Lds + rb + 16384 + boff + n * 1024);
    asm volatile("s_waitcnt lgkmcnt(0)\n\ts_barrier" ::: "memory");
    __builtin_amdgcn_sched_barrier(0);
    __builtin_amdgcn_s_setprio(1);
    #pragma unroll
    for (int j = 0; j < 4; j++)
      #pragma unroll
      for (int n = 0; n < 4; n++) MFMA16(acc[j][n], a[j], b[n]);
    __builtin_amdgcn_s_setprio(0);

    // ---- phase 4: kh=1, mi 4-7; vmcnt(8) confirms Bk0/Ak0/Bk1(t+1) ----
    #pragma unroll
    for (int j = 0; j < 4; j++) a[j] = *(const short8*)(Lds + rb + 16384 + aoff + (4 + j) * 1024);
    if (t + 2 < NK){
      stageU(pB1, rb + 32768 + 16384);
      asm volatile("s_waitcnt vmcnt(8) lgkmcnt(0)\n\ts_barrier" ::: "memory");
    } else {
      asm volatile("s_waitcnt vmcnt(0) lgkmcnt(0)\n\ts_barrier" ::: "memory");
    }
    __builtin_amdgcn_sched_barrier(0);
    __builtin_amdgcn_s_setprio(1);
    #pragma unroll
    for (int j = 0; j < 4; j++)
      #pragma unroll
      for (int n = 0; n < 4; n++) MFMA16(acc[4 + j][n], a[j], b[n]);
    __builtin_amdgcn_s_setprio(0);
  }

  // Epilogue. C/D layout: col = lane&15, row = (lane>>4)*4 + i  (m89/m91).
  char* OutZ = (char*)Out + (size_t)z * strideOutBytes;
  const int colbase = n0 + (wn << 6);
  if constexpr (EPI == 1){
    const int wcol = colbase >> 6;
    #pragma unroll
    for (int mi = 0; mi < 8; mi++){
      #pragma unroll
      for (int i = 0; i < 4; i++){
        int row = m0 + (wm << 7) + mi * 16 + qd * 4 + i;
        unsigned long long w = mbits[(size_t)row * (NT / 64) + wcol];
        unsigned short* po = (unsigned short*)OutZ + (size_t)row * Nn + colbase;
        float rsum = 0.f;
        #pragma unroll
        for (int ni = 0; ni < 4; ni++){
          float vv = acc[mi][ni][i];
          float e = ((w >> (ni * 16 + lm)) & 1ull) ? __expf(vv * 0.03125f) : 0.f;
          rsum += e;
          po[ni * 16 + lm] = f2bf(e);
        }
        // reduce across the 16 lanes (lm) of this qd group -> row total (64 cols)
        rsum += __shfl_xor(rsum, 1, 64);
        rsum += __shfl_xor(rsum, 2, 64);
        rsum += __shfl_xor(rsum, 4, 64);
        rsum += __shfl_xor(rsum, 8, 64);
        if (lm == 0) atomicAdd(rowsums + ((size_t)z << 11) + row, rsum);
      }
    }
  } else if constexpr (EPI == 2){
    #pragma unroll
    for (int mi = 0; mi < 8; mi++){
      #pragma unroll
      for (int i = 0; i < 4; i++){
        int row = m0 + (wm << 7) + mi * 16 + qd * 4 + i;
        float inv = 1.0f / rowsums[((size_t)z << 11) + row];
        #pragma unroll
        for (int ni = 0; ni < 4; ni++){
          int col = colbase + ni * 16 + lm;
          ((float*)OutZ)[(size_t)row * Nn + col] = acc[mi][ni][i] * inv;
        }
      }
    }
  } else {
    if (trOut != nullptr && z == 2){
      // Fused V^T: acc -> LDS [colLocal][token] (528-B padded col-rows),
      // then coalesced 16B stores to trOut[b][emb][token].
      // K-loop's final barrier guarantees all LDS reads complete (each
      // wave's lgkm0 preceded it), so writes here are safe.
      #pragma unroll
      for (int mi = 0; mi < 8; mi++){
        int row0 = (wm << 7) + mi * 16 + qd * 4;      // token within tile, %4==0
        #pragma unroll
        for (int ni = 0; ni < 4; ni++){
          int col = (wn << 6) + ni * 16 + lm;          // emb within tile
          unsigned int lo = (unsigned int)f2bf(acc[mi][ni][0]) |
                            ((unsigned int)f2bf(acc[mi][ni][1]) << 16);
          unsigned int hi = (unsigned int)f2bf(acc[mi][ni][2]) |
                            ((unsigned int)f2bf(acc[mi][ni][3]) << 16);
          uint2v p; p.x = lo; p.y = hi;
          *(uint2v*)(Lds + col * 528 + row0 * 2) = p;  // 8B store, 8-aligned
        }
      }
      __syncthreads();
      int bb = m0 >> 11, tb = m0 & 2047;               // batch, token base
      unsigned short* base = trOut + (size_t)bb * NE * NT + (size_t)n0 * NT + tb;
      #pragma unroll
      for (int k2 = 0; k2 < 16; k2++){
        int gid = (k2 << 9) + tid;                     // 0..8191
        int col = gid >> 5, chk = gid & 31;            // 256 cols x 32 chunks
        ushortx8 vv = *(const ushortx8*)(Lds + col * 528 + (chk << 4));
        *(ushortx8*)(base + (size_t)col * NT + (chk << 3)) = vv;
      }
    } else {
      #pragma unroll
      for (int mi = 0; mi < 8; mi++){
        #pragma unroll
        for (int i = 0; i < 4; i++){
          int row = m0 + (wm << 7) + mi * 16 + qd * 4 + i;
          #pragma unroll
          for (int ni = 0; ni < 4; ni++){
            int col = colbase + ni * 16 + lm;
            ((unsigned short*)OutZ)[(size_t)row * Nn + col] = f2bf(acc[mi][ni][i]);
          }
        }
      }
    }
  }
}

extern "C" void kernel_launch(void* const* d_in, const int* in_sizes, int n_in,
                              void* d_out, int out_size, void* d_ws, size_t ws_size,
                              hipStream_t stream){
  const float* q  = (const float*)d_in[0];
  const float* k  = (const float*)d_in[1];
  const float* v  = (const float*)d_in[2];
  const int* mask = (const int*)d_in[3];
  const float* Wq = (const float*)d_in[4];
  const float* Wk = (const float*)d_in[5];
  const float* Wv = (const float*)d_in[6];

  const size_t BTE = (size_t)NB * NT * NE;     // 16,777,216
  unsigned short* ws   = (unsigned short*)d_ws;
  unsigned short* QKVp = ws;                                    // [3][B*T][E] (V slot holds V^T)
  unsigned short* Sb   = ws + 3 * BTE + BTE;                    // [B][T][T]
  unsigned short* Qin  = ws + 3 * BTE;                          // [3][B*T][E] bf16 inputs
  unsigned short* Wb   = ws + 3 * BTE + BTE + (size_t)NB * NT * NT;  // [3][E][E]
  unsigned long long* mbits = (unsigned long long*)(Wb + (size_t)3 * NE * NE);
  // rowsums [NB][NT] f32 (64 KB) overlays Wb (dead after projections).
  float* rowsums = (float*)Wb;

  unsigned short* Qp  = QKVp;
  unsigned short* Kp  = QKVp + BTE;
  unsigned short* VpT = QKVp + 2 * BTE;        // [B][E][T], written by proj epilogue

  // 1) fp32 -> bf16: inputs q,k,v (Qin aliases the region later used by Sb;
  //    q-part read by proj, so V^T must NOT live there -> it lives in Vp slot)
  cvt3<<<dim3(16384, 3), 256, 0, stream>>>(q, k, v, Qin, (int)(BTE / 4));
  // 2) weights -> bf16 + mask -> bitmask, one dispatch
  prep<<<3328, 256, 0, stream>>>(Wq, Wk, Wv, Wb, mask, mbits);

  // 3) projections: [3 x] (16384 x 1024 x 1024); gx=4, gy=64, gz=3.
  //    z==2 (V) writes V^T into VpT via fused LDS transpose.
  gemm_nt<0><<<768, 512, 0, stream>>>(
      Qin, (long)BTE, Wb, (long)NE * NE,
      QKVp, (long)BTE * 2, nullptr, nullptr, VpT, NE, 4, 64);

  // 4) zero rowsums (Wb dead now; must precede QK^T's atomics)
  hipMemsetAsync(rowsums, 0, (size_t)NB * NT * sizeof(float), stream);

  // 5) S' = mask ? exp(QK^T/32) : 0, + per-row sums; gx=8, gy=8, gz=8
  gemm_nt<1><<<512, 512, 0, stream>>>(
      Qp, (long)NT * NE, Kp, (long)NT * NE,
      Sb, (long)NT * NT * 2, mbits, rowsums, nullptr, NE, 8, 8);

  // 6) O = (S' V) / rowsum; gx=4, gy=8, gz=8, fp32 out
  gemm_nt<2><<<256, 512, 0, stream>>>(
      Sb, (long)NT * NT, VpT, (long)NE * NT,
      d_out, (long)NT * NE * 4, nullptr, rowsums, nullptr, NT, 4, 8);
}